// Round 1
// 68.386 us; speedup vs baseline: 1.0450x; 1.0450x over previous
//
#include <hip/hip_runtime.h>

// P=2048 patches, D=256. loss = mean_{p,i,j} |q[p,i]q[p,j] - k[p,i]k[p,j]|
//
// R5: compute body identical to R4 (wave-per-patch, LDS float4 broadcast
// reads, packed-fp32 VOP3P inner math). Change: epilogue.
//   R4: 512 blocks all atomicAdd the SAME d_out address in a burst ->
//       serialized device-scope RMW tail (~25 us, instruction-mix
//       independent -- explains why R3->R4 VALU cut moved dur_us by ~0).
//   R5: each block plain-stores its partial to d_ws[blockIdx] (distinct
//       addresses, no contention); a 1-block reduce kernel sums the 512
//       partials and WRITES (=) the scaled loss to d_out. Also removes
//       any dependence on the harness's output poison value.

#define PATCHES 2048
#define DIM 256
#define PPB 4   // patches per block (one per wave)

typedef float v2f __attribute__((ext_vector_type(2)));

__global__ __launch_bounds__(256) void patch_l1_partial(
    const float4* __restrict__ q4,
    const float4* __restrict__ k4,
    float* __restrict__ partial)
{
    __shared__ float4 qs[PPB][DIM / 4];   // 4 KB
    __shared__ float4 ks[PPB][DIM / 4];   // 4 KB

    const int t  = threadIdx.x;
    const int p0 = blockIdx.x * PPB;

    // Stage 4 patches (q & k): coalesced, one float4 per thread per array.
    {
        const int lp = t >> 6;    // local patch 0..3
        const int e  = t & 63;    // float4 index within row
        qs[lp][e] = q4[(size_t)(p0 + lp) * (DIM / 4) + e];
        ks[lp][e] = k4[(size_t)(p0 + lp) * (DIM / 4) + e];
    }
    __syncthreads();

    const int wave = t >> 6;      // local patch
    const int lane = t & 63;
    const int half = lane >> 5;   // j-half selector
    const int cg   = lane & 31;   // column group: owns cols 8*cg..8*cg+7

    const float4 qi0 = qs[wave][2 * cg];
    const float4 qi1 = qs[wave][2 * cg + 1];
    const float4 ki0 = ks[wave][2 * cg];
    const float4 ki1 = ks[wave][2 * cg + 1];

    // own columns as scalar arrays for splatting
    const float qc[8] = {qi0.x, qi0.y, qi0.z, qi0.w, qi1.x, qi1.y, qi1.z, qi1.w};
    const float kc[8] = {ki0.x, ki0.y, ki0.z, ki0.w, ki1.x, ki1.y, ki1.z, ki1.w};

    const int jb0 = half * 32;    // 32 float4 steps = 128 j values

    v2f acc0 = {0.f, 0.f}, acc1 = {0.f, 0.f};
    v2f acc2 = {0.f, 0.f}, acc3 = {0.f, 0.f};

#pragma unroll 4
    for (int jb = 0; jb < 32; ++jb) {
        const float4 qj = qs[wave][jb0 + jb];
        const float4 kj = ks[wave][jb0 + jb];
        const v2f qjl = {qj.x, qj.y}, qjh = {qj.z, qj.w};
        const v2f kjl = {kj.x, kj.y}, kjh = {kj.z, kj.w};

#pragma unroll
        for (int c = 0; c < 8; ++c) {
            const v2f qspl = {qc[c], qc[c]};
            const v2f kspl = {kc[c], kc[c]};
            // low pair of j's
            {
                const v2f v = qspl * qjl - kspl * kjl;   // pk_mul + pk_fma
                const v2f a = __builtin_elementwise_max(v, -v); // pk_max, neg mod
                if (c & 1) acc1 += a; else acc0 += a;    // pk_add
            }
            // high pair of j's
            {
                const v2f v = qspl * qjh - kspl * kjh;
                const v2f a = __builtin_elementwise_max(v, -v);
                if (c & 1) acc3 += a; else acc2 += a;
            }
        }
    }

    const v2f accv = (acc0 + acc1) + (acc2 + acc3);
    float acc = accv.x + accv.y;

    // 64-lane shuffle reduction -> one sum per wave
#pragma unroll
    for (int off = 32; off > 0; off >>= 1)
        acc += __shfl_down(acc, off, 64);

    __shared__ float wsum[PPB];
    if (lane == 0) wsum[wave] = acc;
    __syncthreads();

    if (t == 0) {
        // Plain store, distinct address per block: no atomic contention.
        partial[blockIdx.x] = (wsum[0] + wsum[1]) + (wsum[2] + wsum[3]);
    }
}

__global__ __launch_bounds__(512) void patch_l1_reduce(
    const float* __restrict__ partial,
    float* __restrict__ out)
{
    const int t = threadIdx.x;          // 512 threads, one partial each
    float v = partial[t];

#pragma unroll
    for (int off = 32; off > 0; off >>= 1)
        v += __shfl_down(v, off, 64);

    __shared__ float ws[8];
    if ((t & 63) == 0) ws[t >> 6] = v;
    __syncthreads();

    if (t == 0) {
        const float inv_denom =
            1.0f / ((float)PATCHES * (float)DIM * (float)DIM);
        const float s = ((ws[0] + ws[1]) + (ws[2] + ws[3]))
                      + ((ws[4] + ws[5]) + (ws[6] + ws[7]));
        out[0] = s * inv_denom;          // plain store: poison-proof
    }
}

extern "C" void kernel_launch(void* const* d_in, const int* in_sizes, int n_in,
                              void* d_out, int out_size, void* d_ws, size_t ws_size,
                              hipStream_t stream)
{
    const float4* q4 = (const float4*)d_in[0];
    const float4* k4 = (const float4*)d_in[1];
    float* partial = (float*)d_ws;      // 512 floats = 2 KB of workspace
    float* out = (float*)d_out;

    patch_l1_partial<<<PATCHES / PPB, 256, 0, stream>>>(q4, k4, partial);
    patch_l1_reduce<<<1, 512, 0, stream>>>(partial, out);
}

// Round 2
// 66.714 us; speedup vs baseline: 1.0712x; 1.0251x over previous
//
#include <hip/hip_runtime.h>

// P=2048 patches, D=256. loss = mean_{p,i,j} |q[p,i]q[p,j] - k[p,i]k[p,j]|
//
// R6: occupancy fix. R5 post-mortem: atomic removal was only -3us; the
// compute kernel is ~25us vs a ~6.8us VALU-issue floor (pk_f32 is NOT
// double-rate on CDNA4, which is why scalar->packed was neutral). R5 ran
// 512 blocks = 2048 waves = 2 waves/SIMD (25% occupancy cap) -> LDS/dep
// latency leaks into issue gaps.
//   R6: one patch per block, 2048 blocks x 256 threads. The 4 waves of a
//   block split the j-range into quarters (lane bit5 -> eighths), keeping
//   the exact same inner math and the same 2x ds_read_b128 : 64 pk-instr
//   ratio. LDS = 2KB/block -> 8 waves/SIMD (full 32 waves/CU).
// Epilogue: plain store of block partial to d_ws (2048 floats), 1-block
// reduce kernel writes (=) the scaled loss (poison-proof).

#define PATCHES 2048
#define DIM 256

typedef float v2f __attribute__((ext_vector_type(2)));

__global__ __launch_bounds__(256) void patch_l1_partial(
    const float4* __restrict__ q4,
    const float4* __restrict__ k4,
    float* __restrict__ partial)
{
    __shared__ float4 qs[DIM / 4];   // 1 KB
    __shared__ float4 ks[DIM / 4];   // 1 KB

    const int t = threadIdx.x;
    const int p = blockIdx.x;

    // Stage one patch (q & k): two waves each do one coalesced 1KB row.
    if (t < 64) {
        qs[t] = q4[(size_t)p * (DIM / 4) + t];
    } else if (t < 128) {
        ks[t - 64] = k4[(size_t)p * (DIM / 4) + (t - 64)];
    }
    __syncthreads();

    const int wave = t >> 6;      // j-quarter selector (0..3)
    const int lane = t & 63;
    const int half = lane >> 5;   // eighth selector within the quarter
    const int cg   = lane & 31;   // column group: owns cols 8*cg..8*cg+7

    const float4 qi0 = qs[2 * cg];
    const float4 qi1 = qs[2 * cg + 1];
    const float4 ki0 = ks[2 * cg];
    const float4 ki1 = ks[2 * cg + 1];

    // own columns as scalar arrays for splatting (fully unrolled below ->
    // compile-time indexed -> registers, no scratch)
    const float qc[8] = {qi0.x, qi0.y, qi0.z, qi0.w, qi1.x, qi1.y, qi1.z, qi1.w};
    const float kc[8] = {ki0.x, ki0.y, ki0.z, ki0.w, ki1.x, ki1.y, ki1.z, ki1.w};

    // this thread's 8-float4 j-chunk: 32 j values
    const int jb0 = wave * 16 + half * 8;

    v2f acc0 = {0.f, 0.f}, acc1 = {0.f, 0.f};
    v2f acc2 = {0.f, 0.f}, acc3 = {0.f, 0.f};

#pragma unroll
    for (int jb = 0; jb < 8; ++jb) {
        const float4 qj = qs[jb0 + jb];
        const float4 kj = ks[jb0 + jb];
        const v2f qjl = {qj.x, qj.y}, qjh = {qj.z, qj.w};
        const v2f kjl = {kj.x, kj.y}, kjh = {kj.z, kj.w};

#pragma unroll
        for (int c = 0; c < 8; ++c) {
            const v2f qspl = {qc[c], qc[c]};
            const v2f kspl = {kc[c], kc[c]};
            // low pair of j's
            {
                const v2f v = qspl * qjl - kspl * kjl;   // pk_mul + pk_fma
                const v2f a = __builtin_elementwise_max(v, -v); // pk_max, neg mod
                if (c & 1) acc1 += a; else acc0 += a;    // pk_add
            }
            // high pair of j's
            {
                const v2f v = qspl * qjh - kspl * kjh;
                const v2f a = __builtin_elementwise_max(v, -v);
                if (c & 1) acc3 += a; else acc2 += a;
            }
        }
    }

    const v2f accv = (acc0 + acc1) + (acc2 + acc3);
    float acc = accv.x + accv.y;

    // 64-lane shuffle reduction -> one sum per wave
#pragma unroll
    for (int off = 32; off > 0; off >>= 1)
        acc += __shfl_down(acc, off, 64);

    __shared__ float wsum[4];
    if (lane == 0) wsum[wave] = acc;
    __syncthreads();

    if (t == 0) {
        // Plain store, distinct address per block: no atomic contention.
        partial[p] = (wsum[0] + wsum[1]) + (wsum[2] + wsum[3]);
    }
}

__global__ __launch_bounds__(512) void patch_l1_reduce(
    const float* __restrict__ partial,
    float* __restrict__ out)
{
    const int t = threadIdx.x;          // 512 threads, 4 partials each
    float v = (partial[t] + partial[t + 512])
            + (partial[t + 1024] + partial[t + 1536]);

#pragma unroll
    for (int off = 32; off > 0; off >>= 1)
        v += __shfl_down(v, off, 64);

    __shared__ float ws[8];
    if ((t & 63) == 0) ws[t >> 6] = v;
    __syncthreads();

    if (t == 0) {
        const float inv_denom =
            1.0f / ((float)PATCHES * (float)DIM * (float)DIM);
        const float s = ((ws[0] + ws[1]) + (ws[2] + ws[3]))
                      + ((ws[4] + ws[5]) + (ws[6] + ws[7]));
        out[0] = s * inv_denom;          // plain store: poison-proof
    }
}

extern "C" void kernel_launch(void* const* d_in, const int* in_sizes, int n_in,
                              void* d_out, int out_size, void* d_ws, size_t ws_size,
                              hipStream_t stream)
{
    const float4* q4 = (const float4*)d_in[0];
    const float4* k4 = (const float4*)d_in[1];
    float* partial = (float*)d_ws;      // 2048 floats = 8 KB of workspace
    float* out = (float*)d_out;

    patch_l1_partial<<<PATCHES, 256, 0, stream>>>(q4, k4, partial);
    patch_l1_reduce<<<1, 512, 0, stream>>>(partial, out);
}